// Round 3
// baseline (345.342 us; speedup 1.0000x reference)
//
#include <hip/hip_runtime.h>
#include <stdint.h>

#define W_   160
#define H_   96
#define C_   128
#define B_   16
#define NBX  5                  // 160/32
#define NBY  6                  // 96/16
#define TX   32
#define TY   16
#define PXN  8
#define ROWS 18                 // TY + 2 (one dy-triplet)
#define RSTR 44                 // padded row stride: b128 windows at conflict floor
#define CSIZE (ROWS * RSTR)     // 792 floats per channel slice
#define CCH  4                  // channels per LDS chunk
#define CHUNKF (CCH * CSIZE)    // 3168 data floats
#define BUFPAD 3840             // padded buffer: 960 16B slots (5*192), scrap at end
#define NCHUNK (C_ / CCH)       // 32
#define NSLOT (CHUNKF / 4)      // 792 real 16B slots
#define NTHR 192                // 3 waves; wave t -> dy = 3*trip + t - 4
#define NTILE (B_ * NBY * NBX)  // 480
#define NWG   (NTILE * 3)       // 1440 = 8 * 180 (XCD-divisible)

__device__ float g_zero[16];    // zero-initialized at module load; never written

__device__ __forceinline__ void g2l16(const float* g, float* l) {
    __builtin_amdgcn_global_load_lds(
        (const __attribute__((address_space(1))) void*)g,
        (__attribute__((address_space(3))) void*)l, 16, 0, 0);
}

__global__ __launch_bounds__(NTHR, 4) void corr_kernel(
    const float* __restrict__ in1,
    const float* __restrict__ in2,
    float* __restrict__ out)
{
    __shared__ float lds[2 * BUFPAD];   // 30720 B double-buffered in2 chunk

    // XCD-chunked bijective swizzle; trip varies fastest -> tile-sharing blocks co-XCD
    const int L    = (blockIdx.x & 7) * (NWG / 8) + (blockIdx.x >> 3);
    const int tile = L / 3;
    const int trip = L % 3;             // dy = 3*trip + t - 4
    const int b    = tile / (NBY * NBX);
    const int rem  = tile % (NBY * NBX);
    const int by   = rem / NBX;
    const int bx   = rem % NBX;
    const int x0 = bx * TX, y0 = by * TY;

    const size_t HW = (size_t)H_ * W_;
    const float* i1b = in1 + (size_t)b * C_ * HW;
    const float* i2b = in2 + (size_t)b * C_ * HW;

    const int tid  = threadIdx.x;
    const int t    = tid >> 6;          // wave 0..2
    const int lane = tid & 63;
    const int q    = lane & 3;          // x-quad (8 px)
    const int r    = lane >> 2;         // row 0..15

    const int ybase = y0 - 4 + 3 * trip;   // gy of LDS row 0

    // ---- staging slot decode: 5 rounds, slot = tid + k*192 (scrap if >= NSLOT) ----
    int  src[5];
    bool vld[5];
#pragma unroll
    for (int k = 0; k < 5; ++k) {
        const int slot = tid + k * NTHR;
        const bool live = (slot < NSLOT);
        const int e   = (live ? slot : 0) * 4;
        const int cl  = e / CSIZE;
        const int rr  = e % CSIZE;
        const int row = rr / RSTR;
        const int col = rr % RSTR;
        const int gy  = ybase + row;
        const int gx  = x0 - 4 + col;
        vld[k] = live && (col < 40)
               && ((unsigned)gy < (unsigned)H_)
               && ((unsigned)gx <= (unsigned)(W_ - 4));
        src[k] = cl * (int)HW + gy * W_ + gx;
    }

    // Full-wave exec on every g2l16 (linear LDS dest); per-lane validity is on the
    // SOURCE address only: invalid lanes pull 16B of zeros from g_zero.
#define STAGE(dst, chb)                                                        \
    {                                                                          \
        const float* base2 = i2b + (chb);                                      \
        g2l16(vld[0] ? base2 + src[0] : g_zero, (dst) + 4 * tid);              \
        g2l16(vld[1] ? base2 + src[1] : g_zero, (dst) + 4 * tid + 768);        \
        g2l16(vld[2] ? base2 + src[2] : g_zero, (dst) + 4 * tid + 1536);       \
        g2l16(vld[3] ? base2 + src[3] : g_zero, (dst) + 4 * tid + 2304);       \
        g2l16(vld[4] ? base2 + src[4] : g_zero, (dst) + 4 * tid + 3072);       \
    }

    // prologue: stage chunk 0 into buffer 0
    STAGE(lds, 0);
    __syncthreads();   // compiler drains vmcnt(0) before barrier -> buf0 ready

    float acc[PXN][9];
#pragma unroll
    for (int p = 0; p < PXN; ++p)
#pragma unroll
        for (int d = 0; d < 9; ++d) acc[p][d] = 0.f;

    const float* a0p = i1b + (size_t)(y0 + r) * W_ + (x0 + q * PXN);
    const int woff = (r + t) * RSTR + q * PXN;   // window: LDS row r+t, local col 8q

    for (int ch = 0; ch < NCHUNK; ++ch) {
        const float* cbuf = lds + (ch & 1) * BUFPAD;
        if (ch + 1 < NCHUNK) {
            STAGE(lds + ((ch + 1) & 1) * BUFPAD, (ch + 1) * CCH * (int)HW);
        }
#pragma unroll
        for (int cc = 0; cc < CCH; ++cc) {
            const float* ap = a0p + (size_t)(ch * CCH + cc) * HW;
            const float4 a0 = *(const float4*)(ap);
            const float4 a1 = *(const float4*)(ap + 4);
            const float* wp = cbuf + cc * CSIZE + woff;
            const float4 w0 = *(const float4*)(wp);
            const float4 w1 = *(const float4*)(wp + 4);
            const float4 w2 = *(const float4*)(wp + 8);
            const float4 w3 = *(const float4*)(wp + 12);
            const float av[8] = {a0.x, a0.y, a0.z, a0.w, a1.x, a1.y, a1.z, a1.w};
            const float wf[16] = {w0.x, w0.y, w0.z, w0.w,  w1.x, w1.y, w1.z, w1.w,
                                  w2.x, w2.y, w2.z, w2.w,  w3.x, w3.y, w3.z, w3.w};
#pragma unroll
            for (int p = 0; p < PXN; ++p)
#pragma unroll
                for (int d = 0; d < 9; ++d)
                    acc[p][d] = fmaf(av[p], wf[p + d], acc[p][d]);
        }
        __syncthreads();   // drains vmcnt(0): next chunk fully staged before reuse
    }
#undef STAGE

    // ---- epilogue: out[b][(3*trip+t)*9+d][y][x] = acc/128 ----
    const float sc = 1.0f / 128.0f;
    const size_t obase = (((size_t)b * 81 + (size_t)(3 * trip + t) * 9) * H_ + (y0 + r)) * W_
                       + (x0 + q * PXN);
#pragma unroll
    for (int d = 0; d < 9; ++d) {
        float4 o0, o1;
        o0.x = acc[0][d] * sc; o0.y = acc[1][d] * sc; o0.z = acc[2][d] * sc; o0.w = acc[3][d] * sc;
        o1.x = acc[4][d] * sc; o1.y = acc[5][d] * sc; o1.z = acc[6][d] * sc; o1.w = acc[7][d] * sc;
        float* op = out + obase + (size_t)d * HW;
        *(float4*)(op)     = o0;
        *(float4*)(op + 4) = o1;
    }
}

extern "C" void kernel_launch(void* const* d_in, const int* in_sizes, int n_in,
                              void* d_out, int out_size, void* d_ws, size_t ws_size,
                              hipStream_t stream) {
    const float* in1 = (const float*)d_in[0];
    const float* in2 = (const float*)d_in[1];
    float* out = (float*)d_out;
    (void)in_sizes; (void)n_in; (void)out_size; (void)d_ws; (void)ws_size;
    hipLaunchKernelGGL(corr_kernel, dim3(NWG), dim3(NTHR), 0, stream, in1, in2, out);
}